// Round 10
// baseline (293.690 us; speedup 1.0000x reference)
//
#include <hip/hip_runtime.h>
#include <math.h>

#define LSEQ 2048
#define BB 4
#define DD 256
#define NROWS (BB*LSEQ)   // 8192
#define LDBIG 1792

typedef unsigned short u16;
typedef unsigned int u32;
typedef short s16x8 __attribute__((ext_vector_type(8)));
typedef float f32x4 __attribute__((ext_vector_type(4)));

// WT sub-offsets (u16 units)
#define WT_BIG  0         // [1792][256]: q|k|v|qkv|f1
#define WT_LO   458752    // [256][256]
#define WT_G1   524288    // [256][512]: [wg1a^T | W'^T]
#define WT_G2   655360    // [256][256]
#define WT_GO   720896    // [256][256]
#define WT_FF1  786432    // [1024][256]
#define WT_FF2  1048576   // [256][1024]
#define WT_TMP1 1310720   // [256][256] wg1b^T bf16
#define WT_TMP2 1376256   // [256][256] wlo bf16 (row-major)

__device__ __forceinline__ float gelu_f(float x){
    return 0.5f*x*(1.0f+erff(x*0.70710678118654752440f));
}
__device__ __forceinline__ float phi_f(float z){ return z>0.f ? z+1.f : expf(z); }
__device__ __forceinline__ float bf2f(u16 u){ union{u32 i; float f;} x; x.i = ((u32)u)<<16; return x.f; }
__device__ __forceinline__ u16 f2bf(float f){ union{float f; u32 i;} x; x.f = f; u32 r = (x.i + 0x7fff + ((x.i>>16)&1)) >> 16; return (u16)r; }

// ---------------- prep -------------------------------------------------------
// ranges: [0,1280) transpose, [1280,9472) LN, [9472,9537) btab,
// [9537,9669) kvzero, [9669,9733) wlo->bf16 cvt, [9733] b'
struct TransDesc { const float* src; int dstoff; int srcK; int N; int dstStride; int tstart; };
struct TransArgs { TransDesc d[12]; };

__global__ __launch_bounds__(256) void prep_kernel(
    TransArgs args, u16* __restrict__ WT,
    const float* __restrict__ x, const float* __restrict__ g1,
    const float* __restrict__ b1, u16* __restrict__ h,
    const float* __restrict__ emb, const float* __restrict__ we1,
    const float* __restrict__ be1, const float* __restrict__ we2,
    const float* __restrict__ be2, float* __restrict__ btab,
    float* __restrict__ kvz,
    const float* __restrict__ wlo, const float* __restrict__ wg1,
    const float* __restrict__ blo, const float* __restrict__ bg1,
    float* __restrict__ bprime)
{
    int bid = blockIdx.x;
    if (bid < 1280){
        int z = 0;
        #pragma unroll
        for (int i=1;i<12;++i) if (bid >= args.d[i].tstart) z = i;
        TransDesc e = args.d[z];
        int tid = bid - e.tstart;
        int ntx = e.N >> 5;
        int kt = tid / ntx, nt = tid - kt*ntx;
        __shared__ float tile[32][33];
        int tx = threadIdx.x & 31, ty = threadIdx.x >> 5;
        #pragma unroll
        for (int i=0;i<4;++i){
            int k = kt*32 + ty + i*8;
            tile[ty+i*8][tx] = e.src[(size_t)k*e.N + nt*32 + tx];
        }
        __syncthreads();
        #pragma unroll
        for (int i=0;i<4;++i){
            int n = nt*32 + ty + i*8;
            WT[e.dstoff + (size_t)n*e.dstStride + kt*32 + tx] = f2bf(tile[tx][ty+i*8]);
        }
    } else if (bid < 9472){
        int r = bid - 1280; int t = threadIdx.x;
        size_t i = (size_t)r*DD + t;
        float v = x[i];
        float s = v, ss = v*v;
        #pragma unroll
        for (int o=32;o>=1;o>>=1){ s += __shfl_xor(s,o); ss += __shfl_xor(ss,o); }
        __shared__ float sh[8];
        int wave = t>>6, lane = t&63;
        if (lane==0){ sh[wave]=s; sh[4+wave]=ss; }
        __syncthreads();
        float S  = sh[0]+sh[1]+sh[2]+sh[3];
        float SS = sh[4]+sh[5]+sh[6]+sh[7];
        float mu  = S*(1.f/DD);
        float var = SS*(1.f/DD) - mu*mu;
        float inv = rsqrtf(var + 1e-5f);
        h[i] = f2bf((v-mu)*inv*g1[t] + b1[t]);
    } else if (bid < 9537){
        int r = bid - 9472; int j = threadIdx.x;
        float acc = be1[j];
        #pragma unroll 8
        for (int d=0; d<64; ++d) acc += emb[r*64+d]*we1[d*256+j];
        float tv = gelu_f(acc)*we2[j];
        #pragma unroll
        for (int o=32;o>=1;o>>=1) tv += __shfl_xor(tv,o);
        __shared__ float sh2[4];
        int wave = j>>6, lane = j&63;
        if (lane==0) sh2[wave]=tv;
        __syncthreads();
        if (j==0) btab[r] = sh2[0]+sh2[1]+sh2[2]+sh2[3] + be2[0];
    } else if (bid < 9669){
        int idx = (bid - 9537)*256 + threadIdx.x;
        kvz[idx] = 0.f;
    } else if (bid < 9733){
        int idx = (bid - 9669)*1024 + threadIdx.x*4;
        float4 v = *(const float4*)&wlo[idx];
        u32 lo = (u32)f2bf(v.x) | ((u32)f2bf(v.y)<<16);
        u32 hi = (u32)f2bf(v.z) | ((u32)f2bf(v.w)<<16);
        *(u32*)&WT[WT_TMP2 + idx]     = lo;
        *(u32*)&WT[WT_TMP2 + idx + 2] = hi;
    } else {
        int t = threadIdx.x;
        float a = bg1[t];
        for (int m=0;m<256;++m) a += blo[m]*wg1[(size_t)(256+m)*256 + t];
        bprime[t] = a;
    }
}

// ---------------- MFMA bf16 GEMM core (BM=64, BN=128, BK=64) -----------------
template<int ACT, bool FINAL, typename CT>
__device__ __forceinline__ void mgemm_core(
    const u16* __restrict__ A0, const u16* __restrict__ A1, int kswitch, int lda,
    const u16* __restrict__ WT, int Kd,
    const float* __restrict__ bias, int actcol,
    CT* __restrict__ C, int ldc,
    const u16* __restrict__ addsrc, const int* __restrict__ rowmask,
    int row0, int col0)
{
    __shared__ u16 ldsA[4096];
    __shared__ u16 ldsB[8192];
    int t = threadIdx.x;
    int l = t & 63, w = t >> 6;
    int wm = w >> 1, wn = w & 1;

    int s_ar = t >> 2, s_ao = t & 3;
    int aidx1 = (s_ar>>4)*1024 + s_ao*128 + (s_ar&15)*8;
    int aidx2 = aidx1 + 4*128;
    int s_bc = t >> 1, s_bo = (t & 1)*4;
    int bbase = (s_bc>>4)*1024 + (s_bc&15)*8;

    f32x4 acc[2][4];
    #pragma unroll
    for (int mf=0;mf<2;++mf)
        #pragma unroll
        for (int nf=0;nf<4;++nf)
            acc[mf][nf] = (f32x4){0.f,0.f,0.f,0.f};

    uint4 av1, av2, bv0, bv1, bv2, bv3;
    {
        const u16* ap = A0 + (size_t)(row0+s_ar)*lda;
        av1 = *(const uint4*)(ap + s_ao*8);
        av2 = *(const uint4*)(ap + 32 + s_ao*8);
        const u16* bp = WT + (size_t)(col0 + s_bc)*Kd + s_bo*8;
        bv0 = *(const uint4*)(bp); bv1 = *(const uint4*)(bp+8);
        bv2 = *(const uint4*)(bp+16); bv3 = *(const uint4*)(bp+24);
    }

    for (int k0 = 0; k0 < Kd; k0 += 64){
        __syncthreads();
        *(uint4*)&ldsA[aidx1] = av1;
        *(uint4*)&ldsA[aidx2] = av2;
        *(uint4*)&ldsB[bbase + (s_bo  )*128] = bv0;
        *(uint4*)&ldsB[bbase + (s_bo+1)*128] = bv1;
        *(uint4*)&ldsB[bbase + (s_bo+2)*128] = bv2;
        *(uint4*)&ldsB[bbase + (s_bo+3)*128] = bv3;
        __syncthreads();
        int kn = k0 + 64;
        if (kn < Kd){
            const u16* Ab = A0; int kk = kn;
            if (kn >= kswitch){ Ab = A1; kk = kn - kswitch; }
            const u16* ap = Ab + (size_t)(row0+s_ar)*lda + kk;
            av1 = *(const uint4*)(ap + s_ao*8);
            av2 = *(const uint4*)(ap + 32 + s_ao*8);
            const u16* bp = WT + (size_t)(col0 + s_bc)*Kd + kn + s_bo*8;
            bv0 = *(const uint4*)(bp); bv1 = *(const uint4*)(bp+8);
            bv2 = *(const uint4*)(bp+16); bv3 = *(const uint4*)(bp+24);
        }
        #pragma unroll
        for (int s=0;s<2;++s){
            s16x8 af[2], bfr[4];
            #pragma unroll
            for (int mf=0;mf<2;++mf) af[mf] = *(s16x8*)&ldsA[(wm*2+mf)*1024 + (s*4+(l>>4))*128 + (l&15)*8];
            #pragma unroll
            for (int nf=0;nf<4;++nf) bfr[nf] = *(s16x8*)&ldsB[(wn*4+nf)*1024 + (s*4+(l>>4))*128 + (l&15)*8];
            #pragma unroll
            for (int mf=0; mf<2; ++mf)
                #pragma unroll
                for (int nf=0; nf<4; ++nf)
                    acc[mf][nf] = __builtin_amdgcn_mfma_f32_16x16x32_bf16(af[mf], bfr[nf], acc[mf][nf], 0,0,0);
        }
    }

    int lrow = (l>>4)*4, lcol = l&15;
    #pragma unroll
    for (int mf=0; mf<2; ++mf){
        #pragma unroll
        for (int nf=0; nf<4; ++nf){
            int col = col0 + wn*64 + nf*16 + lcol;
            float bv;
            if (ACT==1) bv = (col >= actcol) ? bias[col-actcol] : 0.f;
            else        bv = bias ? bias[col] : 0.f;
            #pragma unroll
            for (int i=0;i<4;++i){
                int row = row0 + wm*32 + mf*16 + lrow + i;
                float v = acc[mf][nf][i] + bv;
                if (ACT==1){ if (col >= actcol) v = gelu_f(v); }
                else if (ACT==2) v = 1.f/(1.f+expf(-v));
                if (FINAL){
                    float mfv = (float)rowmask[row];
                    v = (bf2f(addsrc[(size_t)row*ldc + col]) + v) * mfv;
                }
                if constexpr (sizeof(CT)==2) C[(size_t)row*ldc+col] = (CT)f2bf(v);
                else                         C[(size_t)row*ldc+col] = v;
            }
        }
    }
}

template<int ACT, bool FINAL, typename CT>
__global__ __launch_bounds__(256) void mgemm(
    const u16* __restrict__ A0, const u16* __restrict__ A1, int kswitch, int lda,
    const u16* __restrict__ WT, int Kd,
    const float* __restrict__ bias, int actcol,
    CT* __restrict__ C, int ldc,
    const u16* __restrict__ addsrc, const int* __restrict__ rowmask)
{
    mgemm_core<ACT,FINAL,CT>(A0,A1,kswitch,lda,WT,Kd,bias,actcol,C,ldc,addsrc,rowmask,
                             blockIdx.x*64, blockIdx.y*128);
}

// three independent GEMMs in one dispatch (z selects config)
struct GemmCfg { const u16* A0; const u16* A1; int kswitch; const u16* WT; int Kd;
                 const float* bias; int act; u16* C; };
__global__ __launch_bounds__(256) void mgemm_tri(GemmCfg c0, GemmCfg c1, GemmCfg c2)
{
    GemmCfg c = (blockIdx.z==0) ? c0 : ((blockIdx.z==1) ? c1 : c2);
    if (c.act==1)
        mgemm_core<1,false,u16>(c.A0, c.A1, c.kswitch, 256, c.WT, c.Kd, c.bias, 0,
                                c.C, 256, nullptr, nullptr, blockIdx.x*64, blockIdx.y*128);
    else
        mgemm_core<0,false,u16>(c.A0, c.A1, c.kswitch, 256, c.WT, c.Kd, c.bias, 0,
                                c.C, 256, nullptr, nullptr, blockIdx.x*64, blockIdx.y*128);
}

// ------------- neighbor attention (all-wave softmax, 2 barriers) -------------
__global__ __launch_bounds__(256) void nattn_kernel(
    const u16* __restrict__ nb,
    const int* __restrict__ nbr_idx, const int* __restrict__ nbr_mask,
    const int* __restrict__ rel_pos, const int* __restrict__ mask,
    const float* __restrict__ btab, u16* __restrict__ agg)
{
    int r = blockIdx.x;
    int b = r >> 11;
    int t = threadIdx.x, lane = t&63, wave = t>>6;
    __shared__ float s_w[32];
    __shared__ float s_agg[4][256];
    uint2 qu = *(const uint2*)&nb[(size_t)r*LDBIG + lane*4];
    float q0 = bf2f(qu.x&0xffff), q1 = bf2f(qu.x>>16);
    float q2 = bf2f(qu.y&0xffff), q3 = bf2f(qu.y>>16);
    int mrow = mask[r];

    uint2 kreg[8], vreg[8];
    #pragma unroll
    for (int j=0;j<8;++j){
        int idx = nbr_idx[r*32 + wave*8 + j];
        size_t grow = ((size_t)(b<<11) + idx)*LDBIG;
        kreg[j] = *(const uint2*)&nb[grow + 256 + lane*4];
        vreg[j] = *(const uint2*)&nb[grow + 512 + lane*4];
    }
    float d[8];
    #pragma unroll
    for (int j=0;j<8;++j){
        d[j] = q0*bf2f(kreg[j].x&0xffff) + q1*bf2f(kreg[j].x>>16)
             + q2*bf2f(kreg[j].y&0xffff) + q3*bf2f(kreg[j].y>>16);
    }
    // fold-reduce: result on lane l is full sum for neighbor (l&7)
    #define CMB(a,b,s) ({ float _t = (lane&(s)) ? (a) : (b); float _r = __shfl_xor(_t,(s)); (lane&(s)) ? ((b)+_r) : ((a)+_r); })
    float e10 = CMB(d[0],d[1],1), e11 = CMB(d[2],d[3],1);
    float e12 = CMB(d[4],d[5],1), e13 = CMB(d[6],d[7],1);
    float e20 = CMB(e10,e11,2),   e21 = CMB(e12,e13,2);
    float e3  = CMB(e20,e21,4);
    #undef CMB
    e3 += __shfl_xor(e3,8); e3 += __shfl_xor(e3,16); e3 += __shfl_xor(e3,32);
    if (lane < 8){
        int k = wave*8 + lane;
        int rp = rel_pos[r*32+k];
        rp = rp < -32 ? -32 : (rp > 32 ? 32 : rp);
        float logit = e3*0.0625f + btab[rp+32];
        int am = nbr_mask[r*32+k] * mrow;
        s_w[k] = am ? logit : -3.402823466e38f;
    }
    __syncthreads();
    // all-wave redundant softmax over 32 logits (each 32-half holds full set)
    float lg = s_w[lane & 31];
    float m = lg;
    #pragma unroll
    for (int o=16;o>=1;o>>=1) m = fmaxf(m, __shfl_xor(m,o));
    float e = expf(lg - m);
    float ssum = e;
    #pragma unroll
    for (int o=16;o>=1;o>>=1) ssum += __shfl_xor(ssum,o);
    float wn = e / ssum;   // normalized weight for neighbor (lane&31)
    float4 av = {0.f,0.f,0.f,0.f};
    #pragma unroll
    for (int j=0;j<8;++j){
        float wk = __shfl(wn, wave*8 + j);
        av.x += wk*bf2f(vreg[j].x&0xffff); av.y += wk*bf2f(vreg[j].x>>16);
        av.z += wk*bf2f(vreg[j].y&0xffff); av.w += wk*bf2f(vreg[j].y>>16);
    }
    *(float4*)&s_agg[wave][lane*4] = av;
    __syncthreads();
    float sum = s_agg[0][t]+s_agg[1][t]+s_agg[2][t]+s_agg[3][t];
    agg[(size_t)r*256 + t] = f2bf(sum);
}

// ------------- linear-attn stats (phi on k only; v just masked) --------------
__global__ __launch_bounds__(256) void linstats_kernel(
    const u16* __restrict__ qkv, const int* __restrict__ mask,
    float* __restrict__ kv, float* __restrict__ ksum)
{
    int blk = blockIdx.x;
    int bh = blk >> 4, ch = blk & 15;
    int b = bh >> 3, hh = bh & 7;
    int t = threadIdx.x;
    int d = t >> 3, m4 = (t & 7)*4;
    __shared__ float sk[8][32], sv[8][32];
    float a0=0,a1=0,a2=0,a3=0, aks=0;
    int l0 = ch*128;
    int half = t >> 7, tt = t & 127;
    int lr = tt >> 4, e2 = (tt & 15)*2;
    for (int g8=0; g8<16; ++g8){
        int l = l0 + g8*8 + lr;
        size_t base = ((size_t)b*LSEQ + l)*LDBIG + (half ? 1280 : 1024) + hh*32 + e2;
        u32 u = *(const u32*)&qkv[base];
        float mf = (float)mask[b*LSEQ + l];
        float x0 = bf2f((u16)(u & 0xffff));
        float x1 = bf2f((u16)(u >> 16));
        if (half==0){ sk[lr][e2] = phi_f(x0)*mf; sk[lr][e2+1] = phi_f(x1)*mf; }
        else        { sv[lr][e2] = x0*mf;        sv[lr][e2+1] = x1*mf; }
        __syncthreads();
        #pragma unroll
        for (int rr=0;rr<8;++rr){
            float kd = sk[rr][d];
            a0 += kd*sv[rr][m4]; a1 += kd*sv[rr][m4+1];
            a2 += kd*sv[rr][m4+2]; a3 += kd*sv[rr][m4+3];
            if ((t&7)==0) aks += kd;
        }
        __syncthreads();
    }
    size_t kb = (size_t)bh*1024 + d*32 + m4;
    atomicAdd(&kv[kb+0],a0); atomicAdd(&kv[kb+1],a1);
    atomicAdd(&kv[kb+2],a2); atomicAdd(&kv[kb+3],a3);
    if ((t&7)==0) atomicAdd(&ksum[bh*32+d], aks);
}

// ------------- linear-attn apply ---------------------------------------------
__global__ __launch_bounds__(256) void linapply_kernel(
    const u16* __restrict__ qkv, const float* __restrict__ kv,
    const float* __restrict__ ksum, u16* __restrict__ y)
{
    int r = blockIdx.x; int b = r >> 11;
    int t = threadIdx.x;
    __shared__ float sq[256];
    if (t < 128){
        u32 u = *(const u32*)&qkv[(size_t)r*LDBIG + 768 + t*2];
        sq[t*2]   = phi_f(bf2f((u16)(u & 0xffff)));
        sq[t*2+1] = phi_f(bf2f((u16)(u >> 16)));
    }
    __syncthreads();
    int hh = t>>5, m = t&31;
    const float* kvb = &kv[(size_t)((b<<3)+hh)*1024 + m];
    const float* ksb = &ksum[((b<<3)+hh)*32];
    const float* sqh = &sq[hh*32];
    float acc=0.f, az=0.f;
    #pragma unroll
    for (int dd=0; dd<32; ++dd){
        float qd = sqh[dd];
        acc += qd * kvb[dd*32];
        az  += qd * ksb[dd];
    }
    y[(size_t)r*256 + t] = f2bf(acc / (az + 1e-6f));
}

// ------------- gcombine: g=sigmoid(tg@wg2+bg2) fused with fw/mix/LN ----------
// BM=32, BN=256 (full), K=256. Grid 256 blocks x 256 threads (4 waves).
__global__ __launch_bounds__(256) void gcombine_kernel(
    const u16* __restrict__ tg, const u16* __restrict__ WTg2,
    const float* __restrict__ bg2,
    const u16* __restrict__ h, const u16* __restrict__ agglo,
    const u16* __restrict__ ygo, const u16* __restrict__ bigout,
    const float* __restrict__ wf2, const float* __restrict__ bf2v,
    const int* __restrict__ mask, const float* __restrict__ g2,
    const float* __restrict__ b2,
    u16* __restrict__ x2, u16* __restrict__ hn)
{
    __shared__ u16 ldsA[2048];    // 32 rows x 64 k
    __shared__ u16 ldsB[16384];   // 256 cols x 64 k
    __shared__ float s_fw0[32], s_fw1[32];
    __shared__ float s_rs[4][32], s_rss[4][32];
    int t = threadIdx.x;
    int row0 = blockIdx.x*32;
    int l = t & 63, w = t >> 6;

    // ---- phase 0: fw = softmax2(f1 @ wf2 + bf2) for the block's 32 rows ----
    {
        int rl = t>>3, seg = t&7;
        const u16* f1p = bigout + (size_t)(row0+rl)*LDBIG + 1536 + seg*32;
        float p0=0.f, p1=0.f;
        #pragma unroll
        for (int c=0;c<32;c+=2){
            u32 u = *(const u32*)&f1p[c];
            float a = bf2f((u16)(u&0xffff)), bb = bf2f((u16)(u>>16));
            int col = seg*32+c;
            p0 += a*wf2[col*2]   + bb*wf2[col*2+2];
            p1 += a*wf2[col*2+1] + bb*wf2[col*2+3];
        }
        p0 += __shfl_xor(p0,1); p1 += __shfl_xor(p1,1);
        p0 += __shfl_xor(p0,2); p1 += __shfl_xor(p1,2);
        p0 += __shfl_xor(p0,4); p1 += __shfl_xor(p1,4);
        if ((t&7)==0){
            float P0 = p0 + bf2v[0], P1 = p1 + bf2v[1];
            float mx = fmaxf(P0,P1);
            float e0 = expf(P0-mx), e1 = expf(P1-mx);
            float si = 1.f/(e0+e1);
            s_fw0[rl] = e0*si; s_fw1[rl] = e1*si;
        }
    }

    // ---- MFMA K-loop: g-pre = tg @ wg2^T ----
    int s_ar = t >> 2, s_ao = t & 3;          // t<128 stages A
    int aidx1 = (s_ar>>4)*1024 + s_ao*128 + (s_ar&15)*8;
    int aidx2 = aidx1 + 512;
    int bidx = (t>>4)*1024 + (t&15)*8;        // thread t stages col t (8 octets)

    f32x4 acc[2][4];
    #pragma unroll
    for (int mf=0;mf<2;++mf)
        #pragma unroll
        for (int nf=0;nf<4;++nf)
            acc[mf][nf] = (f32x4){0.f,0.f,0.f,0.f};

    uint4 av1, av2, bv[8];
    {
        if (t < 128){
            const u16* ap = tg + (size_t)(row0+s_ar)*256;
            av1 = *(const uint4*)(ap + s_ao*8);
            av2 = *(const uint4*)(ap + 32 + s_ao*8);
        }
        const u16* bp = WTg2 + (size_t)t*256;
        #pragma unroll
        for (int o=0;o<8;++o) bv[o] = *(const uint4*)(bp + o*8);
    }

    for (int k0 = 0; k0 < 256; k0 += 64){
        __syncthreads();
        if (t < 128){
            *(uint4*)&ldsA[aidx1] = av1;
            *(uint4*)&ldsA[aidx2] = av2;
        }
        #pragma unroll
        for (int o=0;o<8;++o) *(uint4*)&ldsB[bidx + o*128] = bv[o];
        __syncthreads();
        int kn = k0 + 64;
        if (kn < 256){
            if (t < 128){
                const u16* ap = tg + (size_t)(row0+s_ar)*256 + kn;
                av1 = *(const uint4*)(ap + s_ao*8);
                av2 = *(const uint4*)(ap + 32 + s_ao*8);
            }
            const u16* bp = WTg2 + (size_t)t*256 + kn;
            #pragma unroll
            for (int o=0;o<8;++o) bv[o] = *(const uint4*)(bp + o*8);
        }
        #pragma unroll
        for (int s=0;s<2;++s){
            s16x8 af[2], bfr[4];
            #pragma unroll
            for (int mf=0;mf<2;++mf) af[mf] = *(s16x8*)&ldsA[mf*1024 + (s*4+(l>>4))*128 + (l&15)*8];
            #pragma unroll
            for (int nf=0;nf<4;++nf) bfr[nf] = *(s16x8*)&ldsB[(w*4+nf)*1024 + (s*4+(l>>4))*128 + (l&15)*8];
            #pragma unroll
            for (int mf=0; mf<2; ++mf)
                #pragma unroll
                for (int nf=0; nf<4; ++nf)
                    acc[mf][nf] = __builtin_amdgcn_mfma_f32_16x16x32_bf16(af[mf], bfr[nf], acc[mf][nf], 0,0,0);
        }
    }

    // ---- epilogue: g=sigmoid, mix, x2 write, LN stats ----
    int lrow = (l>>4)*4, lcol = l&15;
    float vbuf[2][4][4];
    #pragma unroll
    for (int mf=0; mf<2; ++mf){
        #pragma unroll
        for (int nf=0; nf<4; ++nf){
            int col = w*64 + nf*16 + lcol;
            float bvv = bg2[col];
            #pragma unroll
            for (int i=0;i<4;++i){
                int rloc = mf*16 + lrow + i;
                int row = row0 + rloc;
                float gv = 1.f/(1.f+expf(-(acc[mf][nf][i] + bvv)));
                float mfv = (float)mask[row];
                size_t idx = (size_t)row*256 + col;
                float hv = bf2f(h[idx]), ag = bf2f(agglo[idx]), yy = bf2f(ygo[idx]);
                float f0 = s_fw0[rloc], f1v = s_fw1[rloc];
                float v = f0*((hv + gv*ag)*mfv) + f1v*(hv + yy*mfv);
                x2[idx] = f2bf(v);
                vbuf[mf][nf][i] = v;
            }
        }
    }
    // row sums (each wave holds 64 of the 256 cols for every row)
    #pragma unroll
    for (int mf=0; mf<2; ++mf){
        #pragma unroll
        for (int i=0;i<4;++i){
            float s = vbuf[mf][0][i]+vbuf[mf][1][i]+vbuf[mf][2][i]+vbuf[mf][3][i];
            float ss = vbuf[mf][0][i]*vbuf[mf][0][i]+vbuf[mf][1][i]*vbuf[mf][1][i]
                     + vbuf[mf][2][i]*vbuf[mf][2][i]+vbuf[mf][3][i]*vbuf[mf][3][i];
            #pragma unroll
            for (int o=8;o>=1;o>>=1){ s += __shfl_xor(s,o); ss += __shfl_xor(ss,o); }
            if (lcol==0){
                int rloc = mf*16 + lrow + i;
                s_rs[w][rloc] = s; s_rss[w][rloc] = ss;
            }
        }
    }
    __syncthreads();
    #pragma unroll
    for (int mf=0; mf<2; ++mf){
        #pragma unroll
        for (int i=0;i<4;++i){
            int rloc = mf*16 + lrow + i;
            float S  = s_rs[0][rloc]+s_rs[1][rloc]+s_rs[2][rloc]+s_rs[3][rloc];
            float SS = s_rss[0][rloc]+s_rss[1][rloc]+s_rss[2][rloc]+s_rss[3][rloc];
            float mu  = S*(1.f/DD);
            float var = SS*(1.f/DD) - mu*mu;
            float inv = rsqrtf(var + 1e-5f);
            int row = row0 + rloc;
            #pragma unroll
            for (int nf=0;nf<4;++nf){
                int col = w*64 + nf*16 + lcol;
                float o = (vbuf[mf][nf][i]-mu)*inv*g2[col] + b2[col];
                hn[(size_t)row*256 + col] = f2bf(o);
            }
        }
    }
}

// =============================================================================
extern "C" void kernel_launch(void* const* d_in, const int* in_sizes, int n_in,
                              void* d_out, int out_size, void* d_ws, size_t ws_size,
                              hipStream_t stream)
{
    const float* x        = (const float*)d_in[0];
    const int*   mask     = (const int*)  d_in[1];
    const int*   nbr_idx  = (const int*)  d_in[2];
    const int*   nbr_mask = (const int*)  d_in[3];
    const int*   rel_pos  = (const int*)  d_in[4];
    const float* g1   = (const float*)d_in[5];
    const float* b1   = (const float*)d_in[6];
    const float* wq   = (const float*)d_in[7];
    const float* wk   = (const float*)d_in[8];
    const float* wv   = (const float*)d_in[9];
    const float* relpos_emb = (const float*)d_in[10];
    const float* we1  = (const float*)d_in[11];
    const float* be1  = (const float*)d_in[12];
    const float* we2  = (const float*)d_in[13];
    const float* be2  = (const float*)d_in[14];
    const float* wg1  = (const float*)d_in[15];
    const float* bg1  = (const float*)d_in[16];
    const float* wg2  = (const float*)d_in[17];
    const float* bg2  = (const float*)d_in[18];
    const float* wlo  = (const float*)d_in[19];
    const float* blo  = (const float*)d_in[20];
    const float* wqkv = (const float*)d_in[21];
    const float* wgo  = (const float*)d_in[22];
    const float* wf1  = (const float*)d_in[23];
    const float* bf1  = (const float*)d_in[24];
    const float* wf2  = (const float*)d_in[25];
    const float* bf2  = (const float*)d_in[26];
    const float* g2   = (const float*)d_in[27];
    const float* b2   = (const float*)d_in[28];
    const float* wff1 = (const float*)d_in[29];
    const float* bff1 = (const float*)d_in[30];
    const float* wff2 = (const float*)d_in[31];
    const float* bff2 = (const float*)d_in[32];
    float* out = (float*)d_out;

    unsigned char* wsb = (unsigned char*)d_ws;
    u16* bigout  = (u16*)(wsb + ((size_t)0<<20));   // 8192x1792 bf16; reused for ffn1
    u16* h_bf    = (u16*)(wsb + ((size_t)30<<20));
    u16* agg_bf  = (u16*)(wsb + ((size_t)34<<20));
    u16* agglo_bf= (u16*)(wsb + ((size_t)38<<20));
    u16* x2y_bf  = (u16*)(wsb + ((size_t)42<<20));  // y, then x2
    u16* tg_bf   = (u16*)(wsb + ((size_t)46<<20));
    u16* ygo_bf  = (u16*)(wsb + ((size_t)50<<20));
    u16* hn_bf   = (u16*)(wsb + ((size_t)54<<20));
    u16* WT      = (u16*)(wsb + ((size_t)58<<20));  // 2.88MB
    float* btab  = (float*)(wsb + ((size_t)61<<20)); // 65
    float* kvb   = btab + 128;                       // 32768
    float* ksb   = kvb + 32768;                      // 1024
    float* bprime= ksb + 1024;                       // 256

    TransArgs ta;
    ta.d[0]  = { wq,          WT_BIG + 0,       256,  256,  256,    0 };
    ta.d[1]  = { wk,          WT_BIG + 65536,   256,  256,  256,   64 };
    ta.d[2]  = { wv,          WT_BIG + 131072,  256,  256,  256,  128 };
    ta.d[3]  = { wqkv,        WT_BIG + 196608,  256,  768,  256,  192 };
    ta.d[4]  = { wf1,         WT_BIG + 393216,  256,  256,  256,  384 };
    ta.d[5]  = { wlo,         WT_LO,            256,  256,  256,  448 };
    ta.d[6]  = { wg1,         WT_G1,            256,  256,  512,  512 };  // wg1a^T
    ta.d[7]  = { wg2,         WT_G2,            256,  256,  256,  576 };
    ta.d[8]  = { wgo,         WT_GO,            256,  256,  256,  640 };
    ta.d[9]  = { wff1,        WT_FF1,           256, 1024,  256,  704 };
    ta.d[10] = { wff2,        WT_FF2,          1024,  256, 1024,  960 };
    ta.d[11] = { wg1+65536,   WT_TMP1,          256,  256,  256, 1216 };  // wg1b^T
    // transpose tiles: 1280

    const int KBIG = 1<<30;
    dim3 blk(256);

    // 1. prep: transpose + LN + btab + kvzero + wlo-cvt + b'
    prep_kernel<<<9734, blk, 0, stream>>>(ta, WT, x, g1, b1, h_bf,
                                          relpos_emb, we1, be1, we2, be2, btab, kvb,
                                          wlo, wg1, blo, bg1, bprime);
    // 2. W'^T = wg1b^T @ wlo^T-rows -> WT_G1 second half (ldc=512)
    mgemm<0,false,u16><<<dim3(4,2), blk, 0, stream>>>(WT+WT_TMP1, WT+WT_TMP1, KBIG, 256,
                                                      WT+WT_TMP2, 256, nullptr, 0,
                                                      WT+WT_G1+256, 512, nullptr, nullptr);
    // 3. big: [nb(q|k|v) | qkv(qg|kg|vg) | gelu(f1)+bf1] = h @ WT_BIG
    mgemm<1,false,u16><<<dim3(128,14), blk, 0, stream>>>(h_bf, h_bf, KBIG, 256, WT+WT_BIG, 256, bf1, 1536, bigout, LDBIG, nullptr, nullptr);
    // 4-5. linear attention
    linstats_kernel<<<512, blk, 0, stream>>>(bigout, mask, kvb, ksb);
    linapply_kernel<<<NROWS, blk, 0, stream>>>(bigout, kvb, ksb, x2y_bf);   // y
    // 6. neighbor attention
    nattn_kernel<<<NROWS, blk, 0, stream>>>(bigout, nbr_idx, nbr_mask, rel_pos, mask, btab, agg_bf);
    // 7. tri: ygo = y@wgo ; agglo = agg@wlo + blo ; t1 = gelu(h@wg1a + agg@W' + b')
    {
        GemmCfg cgo = { x2y_bf, x2y_bf, KBIG, WT+WT_GO, 256, nullptr, 0, ygo_bf };
        GemmCfg clo = { agg_bf, agg_bf, KBIG, WT+WT_LO, 256, blo,     0, agglo_bf };
        GemmCfg cg1 = { h_bf,   agg_bf, 256,  WT+WT_G1, 512, bprime,  1, tg_bf };
        mgemm_tri<<<dim3(128,2,3), blk, 0, stream>>>(cgo, clo, cg1);
    }
    // 8. gcombine: g=sigmoid(tg@wg2+bg2) fused with fw softmax + mix + LN
    gcombine_kernel<<<256, blk, 0, stream>>>(tg_bf, WT+WT_G2, bg2,
                                             h_bf, agglo_bf, ygo_bf, bigout,
                                             wf2, bf2, mask, g2, b2, x2y_bf, hn_bf);
    // 9. ffn1 = gelu(hn@wff1 + bff1) -> bigout
    mgemm<1,false,u16><<<dim3(128,8), blk, 0, stream>>>(hn_bf, hn_bf, KBIG, 256, WT+WT_FF1, 256, bff1, 0, bigout, 1024, nullptr, nullptr);
    // 10. out = (x2 + ffn1@wff2 + bff2)*mf
    mgemm<0,true,float><<<dim3(128,2), blk, 0, stream>>>(bigout, bigout, KBIG, 1024, WT+WT_FF2, 1024, bff2, 0, out, 256, x2y_bf, mask);
}

// Round 13
// 282.716 us; speedup vs baseline: 1.0388x; 1.0388x over previous
//
#include <hip/hip_runtime.h>
#include <math.h>

#define LSEQ 2048
#define BB 4
#define DD 256
#define NROWS (BB*LSEQ)   // 8192
#define LDBIG 1792

typedef unsigned short u16;
typedef unsigned int u32;
typedef short s16x8 __attribute__((ext_vector_type(8)));
typedef float f32x4 __attribute__((ext_vector_type(4)));

// WT sub-offsets (u16 units)
#define WT_BIG  0         // [1792][256]: q|k|v|qkv|f1
#define WT_LO   458752    // [256][256]
#define WT_G1   524288    // [256][512]: [wg1a^T | W'^T]
#define WT_G2   655360    // [256][256]
#define WT_GO   720896    // [256][256]
#define WT_FF1  786432    // [1024][256]
#define WT_FF2  1048576   // [256][1024]
#define WT_TMP1 1310720   // [256][256] wg1b^T bf16
#define WT_TMP2 1376256   // [256][256] wlo bf16 (row-major)

__device__ __forceinline__ float gelu_f(float x){
    return 0.5f*x*(1.0f+erff(x*0.70710678118654752440f));
}
__device__ __forceinline__ float phi_f(float z){ return z>0.f ? z+1.f : expf(z); }
__device__ __forceinline__ float bf2f(u16 u){ union{u32 i; float f;} x; x.i = ((u32)u)<<16; return x.f; }
__device__ __forceinline__ u16 f2bf(float f){ union{float f; u32 i;} x; x.f = f; u32 r = (x.i + 0x7fff + ((x.i>>16)&1)) >> 16; return (u16)r; }

// ---------------- prep -------------------------------------------------------
// ranges: [0,1280) transpose, [1280,9472) LN, [9472,9537) btab,
// [9537,9669) kvzero, [9669,9733) wlo->bf16 cvt, [9733] b'
struct TransDesc { const float* src; int dstoff; int srcK; int N; int dstStride; int tstart; };
struct TransArgs { TransDesc d[12]; };

__global__ __launch_bounds__(256) void prep_kernel(
    TransArgs args, u16* __restrict__ WT,
    const float* __restrict__ x, const float* __restrict__ g1,
    const float* __restrict__ b1, u16* __restrict__ h,
    const float* __restrict__ emb, const float* __restrict__ we1,
    const float* __restrict__ be1, const float* __restrict__ we2,
    const float* __restrict__ be2, float* __restrict__ btab,
    float* __restrict__ kvz,
    const float* __restrict__ wlo, const float* __restrict__ wg1,
    const float* __restrict__ blo, const float* __restrict__ bg1,
    float* __restrict__ bprime)
{
    int bid = blockIdx.x;
    if (bid < 1280){
        int z = 0;
        #pragma unroll
        for (int i=1;i<12;++i) if (bid >= args.d[i].tstart) z = i;
        TransDesc e = args.d[z];
        int tid = bid - e.tstart;
        int ntx = e.N >> 5;
        int kt = tid / ntx, nt = tid - kt*ntx;
        __shared__ float tile[32][33];
        int tx = threadIdx.x & 31, ty = threadIdx.x >> 5;
        #pragma unroll
        for (int i=0;i<4;++i){
            int k = kt*32 + ty + i*8;
            tile[ty+i*8][tx] = e.src[(size_t)k*e.N + nt*32 + tx];
        }
        __syncthreads();
        #pragma unroll
        for (int i=0;i<4;++i){
            int n = nt*32 + ty + i*8;
            WT[e.dstoff + (size_t)n*e.dstStride + kt*32 + tx] = f2bf(tile[tx][ty+i*8]);
        }
    } else if (bid < 9472){
        int r = bid - 1280; int t = threadIdx.x;
        size_t i = (size_t)r*DD + t;
        float v = x[i];
        float s = v, ss = v*v;
        #pragma unroll
        for (int o=32;o>=1;o>>=1){ s += __shfl_xor(s,o); ss += __shfl_xor(ss,o); }
        __shared__ float sh[8];
        int wave = t>>6, lane = t&63;
        if (lane==0){ sh[wave]=s; sh[4+wave]=ss; }
        __syncthreads();
        float S  = sh[0]+sh[1]+sh[2]+sh[3];
        float SS = sh[4]+sh[5]+sh[6]+sh[7];
        float mu  = S*(1.f/DD);
        float var = SS*(1.f/DD) - mu*mu;
        float inv = rsqrtf(var + 1e-5f);
        h[i] = f2bf((v-mu)*inv*g1[t] + b1[t]);
    } else if (bid < 9537){
        int r = bid - 9472; int j = threadIdx.x;
        float acc = be1[j];
        #pragma unroll 8
        for (int d=0; d<64; ++d) acc += emb[r*64+d]*we1[d*256+j];
        float tv = gelu_f(acc)*we2[j];
        #pragma unroll
        for (int o=32;o>=1;o>>=1) tv += __shfl_xor(tv,o);
        __shared__ float sh2[4];
        int wave = j>>6, lane = j&63;
        if (lane==0) sh2[wave]=tv;
        __syncthreads();
        if (j==0) btab[r] = sh2[0]+sh2[1]+sh2[2]+sh2[3] + be2[0];
    } else if (bid < 9669){
        int idx = (bid - 9537)*256 + threadIdx.x;
        kvz[idx] = 0.f;
    } else if (bid < 9733){
        int idx = (bid - 9669)*1024 + threadIdx.x*4;
        float4 v = *(const float4*)&wlo[idx];
        u32 lo = (u32)f2bf(v.x) | ((u32)f2bf(v.y)<<16);
        u32 hi = (u32)f2bf(v.z) | ((u32)f2bf(v.w)<<16);
        *(u32*)&WT[WT_TMP2 + idx]     = lo;
        *(u32*)&WT[WT_TMP2 + idx + 2] = hi;
    } else {
        int t = threadIdx.x;
        float a = bg1[t];
        for (int m=0;m<256;++m) a += blo[m]*wg1[(size_t)(256+m)*256 + t];
        bprime[t] = a;
    }
}

// ---------------- MFMA bf16 GEMM core (BM=64, BN=128, BK=64) -----------------
template<int ACT, bool FINAL, typename CT>
__device__ __forceinline__ void mgemm_core(
    const u16* __restrict__ A0, const u16* __restrict__ A1, int kswitch, int lda,
    const u16* __restrict__ WT, int Kd,
    const float* __restrict__ bias, int actcol,
    CT* __restrict__ C, int ldc,
    const u16* __restrict__ addsrc, const int* __restrict__ rowmask,
    int row0, int col0)
{
    __shared__ u16 ldsA[4096];
    __shared__ u16 ldsB[8192];
    int t = threadIdx.x;
    int l = t & 63, w = t >> 6;
    int wm = w >> 1, wn = w & 1;

    int s_ar = t >> 2, s_ao = t & 3;
    int aidx1 = (s_ar>>4)*1024 + s_ao*128 + (s_ar&15)*8;
    int aidx2 = aidx1 + 4*128;
    int s_bc = t >> 1, s_bo = (t & 1)*4;
    int bbase = (s_bc>>4)*1024 + (s_bc&15)*8;

    f32x4 acc[2][4];
    #pragma unroll
    for (int mf=0;mf<2;++mf)
        #pragma unroll
        for (int nf=0;nf<4;++nf)
            acc[mf][nf] = (f32x4){0.f,0.f,0.f,0.f};

    uint4 av1, av2, bv0, bv1, bv2, bv3;
    {
        const u16* ap = A0 + (size_t)(row0+s_ar)*lda;
        av1 = *(const uint4*)(ap + s_ao*8);
        av2 = *(const uint4*)(ap + 32 + s_ao*8);
        const u16* bp = WT + (size_t)(col0 + s_bc)*Kd + s_bo*8;
        bv0 = *(const uint4*)(bp); bv1 = *(const uint4*)(bp+8);
        bv2 = *(const uint4*)(bp+16); bv3 = *(const uint4*)(bp+24);
    }

    for (int k0 = 0; k0 < Kd; k0 += 64){
        __syncthreads();
        *(uint4*)&ldsA[aidx1] = av1;
        *(uint4*)&ldsA[aidx2] = av2;
        *(uint4*)&ldsB[bbase + (s_bo  )*128] = bv0;
        *(uint4*)&ldsB[bbase + (s_bo+1)*128] = bv1;
        *(uint4*)&ldsB[bbase + (s_bo+2)*128] = bv2;
        *(uint4*)&ldsB[bbase + (s_bo+3)*128] = bv3;
        __syncthreads();
        int kn = k0 + 64;
        if (kn < Kd){
            const u16* Ab = A0; int kk = kn;
            if (kn >= kswitch){ Ab = A1; kk = kn - kswitch; }
            const u16* ap = Ab + (size_t)(row0+s_ar)*lda + kk;
            av1 = *(const uint4*)(ap + s_ao*8);
            av2 = *(const uint4*)(ap + 32 + s_ao*8);
            const u16* bp = WT + (size_t)(col0 + s_bc)*Kd + kn + s_bo*8;
            bv0 = *(const uint4*)(bp); bv1 = *(const uint4*)(bp+8);
            bv2 = *(const uint4*)(bp+16); bv3 = *(const uint4*)(bp+24);
        }
        #pragma unroll
        for (int s=0;s<2;++s){
            s16x8 af[2], bfr[4];
            #pragma unroll
            for (int mf=0;mf<2;++mf) af[mf] = *(s16x8*)&ldsA[(wm*2+mf)*1024 + (s*4+(l>>4))*128 + (l&15)*8];
            #pragma unroll
            for (int nf=0;nf<4;++nf) bfr[nf] = *(s16x8*)&ldsB[(wn*4+nf)*1024 + (s*4+(l>>4))*128 + (l&15)*8];
            #pragma unroll
            for (int mf=0; mf<2; ++mf)
                #pragma unroll
                for (int nf=0; nf<4; ++nf)
                    acc[mf][nf] = __builtin_amdgcn_mfma_f32_16x16x32_bf16(af[mf], bfr[nf], acc[mf][nf], 0,0,0);
        }
    }

    int lrow = (l>>4)*4, lcol = l&15;
    #pragma unroll
    for (int mf=0; mf<2; ++mf){
        #pragma unroll
        for (int nf=0; nf<4; ++nf){
            int col = col0 + wn*64 + nf*16 + lcol;
            float bv;
            if (ACT==1) bv = (col >= actcol) ? bias[col-actcol] : 0.f;
            else        bv = bias ? bias[col] : 0.f;
            #pragma unroll
            for (int i=0;i<4;++i){
                int row = row0 + wm*32 + mf*16 + lrow + i;
                float v = acc[mf][nf][i] + bv;
                if (ACT==1){ if (col >= actcol) v = gelu_f(v); }
                else if (ACT==2) v = 1.f/(1.f+expf(-v));
                if (FINAL){
                    float mfv = (float)rowmask[row];
                    v = (bf2f(addsrc[(size_t)row*ldc + col]) + v) * mfv;
                }
                if constexpr (sizeof(CT)==2) C[(size_t)row*ldc+col] = (CT)f2bf(v);
                else                         C[(size_t)row*ldc+col] = v;
            }
        }
    }
}

template<int ACT, bool FINAL, typename CT>
__global__ __launch_bounds__(256) void mgemm(
    const u16* __restrict__ A0, const u16* __restrict__ A1, int kswitch, int lda,
    const u16* __restrict__ WT, int Kd,
    const float* __restrict__ bias, int actcol,
    CT* __restrict__ C, int ldc,
    const u16* __restrict__ addsrc, const int* __restrict__ rowmask)
{
    mgemm_core<ACT,FINAL,CT>(A0,A1,kswitch,lda,WT,Kd,bias,actcol,C,ldc,addsrc,rowmask,
                             blockIdx.x*64, blockIdx.y*128);
}

// three independent GEMMs in one dispatch (z selects config)
struct GemmCfg { const u16* A0; const u16* A1; int kswitch; const u16* WT; int Kd;
                 const float* bias; int act; u16* C; };
__global__ __launch_bounds__(256) void mgemm_tri(GemmCfg c0, GemmCfg c1, GemmCfg c2)
{
    GemmCfg c = (blockIdx.z==0) ? c0 : ((blockIdx.z==1) ? c1 : c2);
    if (c.act==1)
        mgemm_core<1,false,u16>(c.A0, c.A1, c.kswitch, 256, c.WT, c.Kd, c.bias, 0,
                                c.C, 256, nullptr, nullptr, blockIdx.x*64, blockIdx.y*128);
    else
        mgemm_core<0,false,u16>(c.A0, c.A1, c.kswitch, 256, c.WT, c.Kd, c.bias, 0,
                                c.C, 256, nullptr, nullptr, blockIdx.x*64, blockIdx.y*128);
}

// ------------- fused neighbor-attn + linear-attn apply -----------------------
// all-wave softmax (2 barriers); V prefetched into regs; shares the row's reads.
__global__ __launch_bounds__(256) void lg_kernel(
    const u16* __restrict__ nb,
    const int* __restrict__ nbr_idx, const int* __restrict__ nbr_mask,
    const int* __restrict__ rel_pos, const int* __restrict__ mask,
    const float* __restrict__ btab, u16* __restrict__ agg,
    const float* __restrict__ kv, const float* __restrict__ ksum,
    u16* __restrict__ y)
{
    int r = blockIdx.x;
    int b = r >> 11;
    int t = threadIdx.x, lane = t&63, wave = t>>6;
    __shared__ float s_w[32];
    __shared__ float s_agg[4][256];
    __shared__ float sq[256];
    uint2 qu = *(const uint2*)&nb[(size_t)r*LDBIG + lane*4];
    float q0 = bf2f(qu.x&0xffff), q1 = bf2f(qu.x>>16);
    float q2 = bf2f(qu.y&0xffff), q3 = bf2f(qu.y>>16);
    int mrow = mask[r];

    uint2 kreg[8], vreg[8];
    #pragma unroll
    for (int j=0;j<8;++j){
        int idx = nbr_idx[r*32 + wave*8 + j];
        size_t grow = ((size_t)(b<<11) + idx)*LDBIG;
        kreg[j] = *(const uint2*)&nb[grow + 256 + lane*4];
        vreg[j] = *(const uint2*)&nb[grow + 512 + lane*4];
    }
    float d[8];
    #pragma unroll
    for (int j=0;j<8;++j){
        d[j] = q0*bf2f(kreg[j].x&0xffff) + q1*bf2f(kreg[j].x>>16)
             + q2*bf2f(kreg[j].y&0xffff) + q3*bf2f(kreg[j].y>>16);
    }
    // fold-reduce: result on lane l is full sum for neighbor (l&7)
    #define CMB(a,b,s) ({ float _t = (lane&(s)) ? (a) : (b); float _r = __shfl_xor(_t,(s)); (lane&(s)) ? ((b)+_r) : ((a)+_r); })
    float e10 = CMB(d[0],d[1],1), e11 = CMB(d[2],d[3],1);
    float e12 = CMB(d[4],d[5],1), e13 = CMB(d[6],d[7],1);
    float e20 = CMB(e10,e11,2),   e21 = CMB(e12,e13,2);
    float e3  = CMB(e20,e21,4);
    #undef CMB
    e3 += __shfl_xor(e3,8); e3 += __shfl_xor(e3,16); e3 += __shfl_xor(e3,32);
    if (lane < 8){
        int k = wave*8 + lane;
        int rp = rel_pos[r*32+k];
        rp = rp < -32 ? -32 : (rp > 32 ? 32 : rp);
        float logit = e3*0.0625f + btab[rp+32];
        int am = nbr_mask[r*32+k] * mrow;
        s_w[k] = am ? logit : -3.402823466e38f;
    }
    // stage linapply q-row (phi(qg)) while logits settle
    if (t < 128){
        u32 u = *(const u32*)&nb[(size_t)r*LDBIG + 768 + t*2];
        sq[t*2]   = phi_f(bf2f((u16)(u & 0xffff)));
        sq[t*2+1] = phi_f(bf2f((u16)(u >> 16)));
    }
    __syncthreads();
    // all-wave redundant softmax over 32 logits
    float lg = s_w[lane & 31];
    float m = lg;
    #pragma unroll
    for (int o=16;o>=1;o>>=1) m = fmaxf(m, __shfl_xor(m,o));
    float e = expf(lg - m);
    float ssum = e;
    #pragma unroll
    for (int o=16;o>=1;o>>=1) ssum += __shfl_xor(ssum,o);
    float wn = e / ssum;
    float4 av = {0.f,0.f,0.f,0.f};
    #pragma unroll
    for (int j=0;j<8;++j){
        float wk = __shfl(wn, wave*8 + j);
        av.x += wk*bf2f(vreg[j].x&0xffff); av.y += wk*bf2f(vreg[j].x>>16);
        av.z += wk*bf2f(vreg[j].y&0xffff); av.w += wk*bf2f(vreg[j].y>>16);
    }
    *(float4*)&s_agg[wave][lane*4] = av;
    __syncthreads();
    float sum = s_agg[0][t]+s_agg[1][t]+s_agg[2][t]+s_agg[3][t];
    agg[(size_t)r*256 + t] = f2bf(sum);

    // ---- linear-attn apply for the same row ----
    int hh = t>>5, mm = t&31;
    const float* kvb = &kv[(size_t)((b<<3)+hh)*1024 + mm];
    const float* ksb = &ksum[((b<<3)+hh)*32];
    const float* sqh = &sq[hh*32];
    float acc=0.f, az=0.f;
    #pragma unroll
    for (int dd=0; dd<32; ++dd){
        float qd = sqh[dd];
        acc += qd * kvb[dd*32];
        az  += qd * ksb[dd];
    }
    y[(size_t)r*256 + t] = f2bf(acc / (az + 1e-6f));
}

// ------------- linear-attn stats (phi on k only; v just masked) --------------
__global__ __launch_bounds__(256) void linstats_kernel(
    const u16* __restrict__ qkv, const int* __restrict__ mask,
    float* __restrict__ kv, float* __restrict__ ksum)
{
    int blk = blockIdx.x;
    int bh = blk >> 4, ch = blk & 15;
    int b = bh >> 3, hh = bh & 7;
    int t = threadIdx.x;
    int d = t >> 3, m4 = (t & 7)*4;
    __shared__ float sk[8][32], sv[8][32];
    float a0=0,a1=0,a2=0,a3=0, aks=0;
    int l0 = ch*128;
    int half = t >> 7, tt = t & 127;
    int lr = tt >> 4, e2 = (tt & 15)*2;
    for (int g8=0; g8<16; ++g8){
        int l = l0 + g8*8 + lr;
        size_t base = ((size_t)b*LSEQ + l)*LDBIG + (half ? 1280 : 1024) + hh*32 + e2;
        u32 u = *(const u32*)&qkv[base];
        float mf = (float)mask[b*LSEQ + l];
        float x0 = bf2f((u16)(u & 0xffff));
        float x1 = bf2f((u16)(u >> 16));
        if (half==0){ sk[lr][e2] = phi_f(x0)*mf; sk[lr][e2+1] = phi_f(x1)*mf; }
        else        { sv[lr][e2] = x0*mf;        sv[lr][e2+1] = x1*mf; }
        __syncthreads();
        #pragma unroll
        for (int rr=0;rr<8;++rr){
            float kd = sk[rr][d];
            a0 += kd*sv[rr][m4]; a1 += kd*sv[rr][m4+1];
            a2 += kd*sv[rr][m4+2]; a3 += kd*sv[rr][m4+3];
            if ((t&7)==0) aks += kd;
        }
        __syncthreads();
    }
    size_t kb = (size_t)bh*1024 + d*32 + m4;
    atomicAdd(&kv[kb+0],a0); atomicAdd(&kv[kb+1],a1);
    atomicAdd(&kv[kb+2],a2); atomicAdd(&kv[kb+3],a3);
    if ((t&7)==0) atomicAdd(&ksum[bh*32+d], aks);
}

// ------------- combine (+inline fw softmax): x2, hn = LN(x2) -----------------
__global__ __launch_bounds__(128) void combine_kernel(
    const u16* __restrict__ h, const u16* __restrict__ agglo,
    const u16* __restrict__ g, const u16* __restrict__ ygo,
    const u16* __restrict__ bigout, const float* __restrict__ wf2,
    const float* __restrict__ bf2v, const int* __restrict__ mask,
    const float* __restrict__ g2, const float* __restrict__ b2,
    u16* __restrict__ x2, u16* __restrict__ hn)
{
    int r = blockIdx.x, t = threadIdx.x;
    int wave = t>>6, lane = t&63;
    // ---- fw = softmax2(f1 @ wf2 + bf2) ----
    u32 fu = *(const u32*)&bigout[(size_t)r*LDBIG + 1536 + t*2];
    float fa = bf2f((u16)(fu&0xffff)), fb = bf2f((u16)(fu>>16));
    int dd = t*2;
    float p0 = fa*wf2[dd*2]   + fb*wf2[dd*2+2];
    float p1 = fa*wf2[dd*2+1] + fb*wf2[dd*2+3];
    #pragma unroll
    for (int o=32;o>=1;o>>=1){ p0 += __shfl_xor(p0,o); p1 += __shfl_xor(p1,o); }
    __shared__ float shp[4];
    if (lane==0){ shp[wave]=p0; shp[2+wave]=p1; }
    __syncthreads();
    float P0 = shp[0]+shp[1]+bf2v[0], P1 = shp[2]+shp[3]+bf2v[1];
    float mx = fmaxf(P0,P1);
    float e0 = expf(P0-mx), e1 = expf(P1-mx);
    float f0 = e0/(e0+e1), f1v = e1/(e0+e1);
    // ---- mix + LN ----
    size_t i = (size_t)r*DD + t*2;
    float mf = (float)mask[r];
    u32 hu = *(const u32*)&h[i],  au = *(const u32*)&agglo[i];
    u32 gu = *(const u32*)&g[i],  yu = *(const u32*)&ygo[i];
    float hv0 = bf2f((u16)(hu&0xffff)), hv1 = bf2f((u16)(hu>>16));
    float ag0 = bf2f((u16)(au&0xffff)), ag1 = bf2f((u16)(au>>16));
    float gg0 = bf2f((u16)(gu&0xffff)), gg1 = bf2f((u16)(gu>>16));
    float yy0 = bf2f((u16)(yu&0xffff)), yy1 = bf2f((u16)(yu>>16));
    float v0 = f0*((hv0 + gg0*ag0)*mf) + f1v*(hv0 + yy0*mf);
    float v1 = f0*((hv1 + gg1*ag1)*mf) + f1v*(hv1 + yy1*mf);
    *(u32*)&x2[i] = (u32)f2bf(v0) | ((u32)f2bf(v1)<<16);
    float s = v0+v1, ss = v0*v0+v1*v1;
    #pragma unroll
    for (int o=32;o>=1;o>>=1){ s += __shfl_xor(s,o); ss += __shfl_xor(ss,o); }
    __shared__ float sh[4];
    if (lane==0){ sh[wave]=s; sh[2+wave]=ss; }
    __syncthreads();
    float S  = sh[0]+sh[1];
    float SS = sh[2]+sh[3];
    float mu  = S*(1.f/DD);
    float var = SS*(1.f/DD) - mu*mu;
    float inv = rsqrtf(var + 1e-5f);
    int j0 = t*2;
    float o0 = (v0-mu)*inv*g2[j0]   + b2[j0];
    float o1 = (v1-mu)*inv*g2[j0+1] + b2[j0+1];
    *(u32*)&hn[i] = (u32)f2bf(o0) | ((u32)f2bf(o1)<<16);
}

// =============================================================================
extern "C" void kernel_launch(void* const* d_in, const int* in_sizes, int n_in,
                              void* d_out, int out_size, void* d_ws, size_t ws_size,
                              hipStream_t stream)
{
    const float* x        = (const float*)d_in[0];
    const int*   mask     = (const int*)  d_in[1];
    const int*   nbr_idx  = (const int*)  d_in[2];
    const int*   nbr_mask = (const int*)  d_in[3];
    const int*   rel_pos  = (const int*)  d_in[4];
    const float* g1   = (const float*)d_in[5];
    const float* b1   = (const float*)d_in[6];
    const float* wq   = (const float*)d_in[7];
    const float* wk   = (const float*)d_in[8];
    const float* wv   = (const float*)d_in[9];
    const float* relpos_emb = (const float*)d_in[10];
    const float* we1  = (const float*)d_in[11];
    const float* be1  = (const float*)d_in[12];
    const float* we2  = (const float*)d_in[13];
    const float* be2  = (const float*)d_in[14];
    const float* wg1  = (const float*)d_in[15];
    const float* bg1  = (const float*)d_in[16];
    const float* wg2  = (const float*)d_in[17];
    const float* bg2  = (const float*)d_in[18];
    const float* wlo  = (const float*)d_in[19];
    const float* blo  = (const float*)d_in[20];
    const float* wqkv = (const float*)d_in[21];
    const float* wgo  = (const float*)d_in[22];
    const float* wf1  = (const float*)d_in[23];
    const float* bf1  = (const float*)d_in[24];
    const float* wf2  = (const float*)d_in[25];
    const float* bf2  = (const float*)d_in[26];
    const float* g2   = (const float*)d_in[27];
    const float* b2   = (const float*)d_in[28];
    const float* wff1 = (const float*)d_in[29];
    const float* bff1 = (const float*)d_in[30];
    const float* wff2 = (const float*)d_in[31];
    const float* bff2 = (const float*)d_in[32];
    float* out = (float*)d_out;

    unsigned char* wsb = (unsigned char*)d_ws;
    u16* bigout  = (u16*)(wsb + ((size_t)0<<20));   // 8192x1792 bf16; reused for ffn1
    u16* h_bf    = (u16*)(wsb + ((size_t)30<<20));
    u16* agg_bf  = (u16*)(wsb + ((size_t)34<<20));  // later g
    u16* agglo_bf= (u16*)(wsb + ((size_t)38<<20));
    u16* x2y_bf  = (u16*)(wsb + ((size_t)42<<20));  // y, then x2
    u16* tg_bf   = (u16*)(wsb + ((size_t)46<<20));
    u16* ygo_bf  = (u16*)(wsb + ((size_t)50<<20));
    u16* hn_bf   = (u16*)(wsb + ((size_t)54<<20));
    u16* WT      = (u16*)(wsb + ((size_t)58<<20));  // 2.88MB
    float* btab  = (float*)(wsb + ((size_t)61<<20)); // 65
    float* kvb   = btab + 128;                       // 32768
    float* ksb   = kvb + 32768;                      // 1024
    float* bprime= ksb + 1024;                       // 256

    TransArgs ta;
    ta.d[0]  = { wq,          WT_BIG + 0,       256,  256,  256,    0 };
    ta.d[1]  = { wk,          WT_BIG + 65536,   256,  256,  256,   64 };
    ta.d[2]  = { wv,          WT_BIG + 131072,  256,  256,  256,  128 };
    ta.d[3]  = { wqkv,        WT_BIG + 196608,  256,  768,  256,  192 };
    ta.d[4]  = { wf1,         WT_BIG + 393216,  256,  256,  256,  384 };
    ta.d[5]  = { wlo,         WT_LO,            256,  256,  256,  448 };
    ta.d[6]  = { wg1,         WT_G1,            256,  256,  512,  512 };  // wg1a^T
    ta.d[7]  = { wg2,         WT_G2,            256,  256,  256,  576 };
    ta.d[8]  = { wgo,         WT_GO,            256,  256,  256,  640 };
    ta.d[9]  = { wff1,        WT_FF1,           256, 1024,  256,  704 };
    ta.d[10] = { wff2,        WT_FF2,          1024,  256, 1024,  960 };
    ta.d[11] = { wg1+65536,   WT_TMP1,          256,  256,  256, 1216 };  // wg1b^T
    // transpose tiles: 1280

    const int KBIG = 1<<30;
    dim3 blk(256);

    // 1. prep: transpose + LN + btab + kvzero + wlo-cvt + b'
    prep_kernel<<<9734, blk, 0, stream>>>(ta, WT, x, g1, b1, h_bf,
                                          relpos_emb, we1, be1, we2, be2, btab, kvb,
                                          wlo, wg1, blo, bg1, bprime);
    // 2. W'^T = wg1b^T @ wlo rows -> WT_G1 second half (ldc=512)
    mgemm<0,false,u16><<<dim3(4,2), blk, 0, stream>>>(WT+WT_TMP1, WT+WT_TMP1, KBIG, 256,
                                                      WT+WT_TMP2, 256, nullptr, 0,
                                                      WT+WT_G1+256, 512, nullptr, nullptr);
    // 3. big: [nb(q|k|v) | qkv(qg|kg|vg) | gelu(f1)+bf1] = h @ WT_BIG
    mgemm<1,false,u16><<<dim3(128,14), blk, 0, stream>>>(h_bf, h_bf, KBIG, 256, WT+WT_BIG, 256, bf1, 1536, bigout, LDBIG, nullptr, nullptr);
    // 4. linear-attn stats
    linstats_kernel<<<512, blk, 0, stream>>>(bigout, mask, kvb, ksb);
    // 5. fused neighbor-attn + linapply
    lg_kernel<<<NROWS, blk, 0, stream>>>(bigout, nbr_idx, nbr_mask, rel_pos, mask, btab,
                                         agg_bf, kvb, ksb, x2y_bf);
    // 6. tri: ygo = y@wgo ; agglo = agg@wlo + blo ; t1 = gelu(h@wg1a + agg@W' + b')
    {
        GemmCfg cgo = { x2y_bf, x2y_bf, KBIG, WT+WT_GO, 256, nullptr, 0, ygo_bf };
        GemmCfg clo = { agg_bf, agg_bf, KBIG, WT+WT_LO, 256, blo,     0, agglo_bf };
        GemmCfg cg1 = { h_bf,   agg_bf, 256,  WT+WT_G1, 512, bprime,  1, tg_bf };
        mgemm_tri<<<dim3(128,2,3), blk, 0, stream>>>(cgo, clo, cg1);
    }
    // 7. g = sigmoid(tg@wg2 + bg2) -> agg slot
    mgemm<2,false,u16><<<dim3(128,2), blk, 0, stream>>>(tg_bf, tg_bf, KBIG, 256, WT+WT_G2, 256, bg2, 0, agg_bf, 256, nullptr, nullptr);
    // 8. combine (+fw) -> x2 (x2y slot), hn
    combine_kernel<<<NROWS, dim3(128), 0, stream>>>(h_bf, agglo_bf, agg_bf, ygo_bf, bigout, wf2, bf2, mask, g2, b2, x2y_bf, hn_bf);
    // 9. ffn1 = gelu(hn@wff1 + bff1) -> bigout
    mgemm<1,false,u16><<<dim3(128,8), blk, 0, stream>>>(hn_bf, hn_bf, KBIG, 256, WT+WT_FF1, 256, bff1, 0, bigout, 1024, nullptr, nullptr);
    // 10. out = (x2 + ffn1@wff2 + bff2)*mf
    mgemm<0,true,float><<<dim3(128,2), blk, 0, stream>>>(bigout, bigout, KBIG, 1024, WT+WT_FF2, 1024, bff2, 0, out, 256, x2y_bf, mask);
}